// Round 16
// baseline (269.932 us; speedup 1.0000x reference)
//
#include <hip/hip_runtime.h>

// HalfEdgeMeshPool: segment-mean over groups.
// feat: [B, C, N] f32, gid: [B, N] i32 in [0,T), out: [B, C, T] f32.
//
// R1/R2: LDS f32 atomics ~3.2cyc/lane -> 428us floor. R3: random 4B global
// gather = 14.5x over-fetch. R7: 160KB LDS = 1 block/CU -> serialized phases.
// R8/R11/R12: fused row-in-LDS + mt[t][8] + 2x1024thr blocks -> 140us.
// R13-R15: phase-2 micro-opts all null; wave-scaling sublinear => per-CU LDS
// gather pipe saturated (8 issued gathers/group vs E[cnt]=2; compiler
// speculates LDS reads so predication never cut the work).
// R16: bucket groups by cnt (0..8, >=9 heavy). permT = bucket-ordered t;
// packed = dense member indices (c u16/group). Phase 2: per-bucket loops with
// WAVE-UNIFORM c -> exactly c gathers/group (4x fewer lane-gathers), coalesced
// index loads, uniform 1/c multiply. Scattered non-NT 4B stores within the
// block's 80KB row (L2 writeback coalesces; R10's amplification was NT+dup).
static constexpr int B = 8;
static constexpr int C = 256;
static constexpr int N = 40000;
static constexpr int T = 20000;
static constexpr int FTH = 1024;   // fused block threads
static constexpr int OCAP = 4096;  // overflow cap per b (members beyond 8th)

typedef float  f32x4 __attribute__((ext_vector_type(4)));
typedef ushort u16x4 __attribute__((ext_vector_type(4)));

__device__ __forceinline__ ushort f2bf(float v) {
    unsigned u = __float_as_uint(v);
    u += 0x7FFFu + ((u >> 16) & 1u);  // round-to-nearest-even
    return (ushort)(u >> 16);
}
__device__ __forceinline__ float bf2f(ushort u) {
    return __uint_as_float((unsigned)u << 16);
}

// ---- init: cnt=0, head2=0, ocnt=0 ----
__global__ void __launch_bounds__(256) hemp_init_kernel(int* __restrict__ cnt,
                                                        int* __restrict__ head2,
                                                        int* __restrict__ ocnt) {
    const int stride = gridDim.x * 256;
    int i = blockIdx.x * 256 + threadIdx.x;
    for (int k = i; k < B * T; k += stride) { cnt[k] = 0; head2[k] = 0; }
    if (i < B) ocnt[i] = 0;
}

// ---- count (int4): per-(b,t) member counts ----
__global__ void __launch_bounds__(256) hemp_count_kernel(const int* __restrict__ gid,
                                                         int* __restrict__ cnt) {
    int idx = blockIdx.x * 256 + threadIdx.x;
    if (idx >= B * N / 4) return;
    const int b = idx / (N / 4);
    const int i4 = idx - b * (N / 4);
    const int4 g = reinterpret_cast<const int4*>(gid + (size_t)b * N)[i4];
    int* cb = cnt + b * T;
    atomicAdd(&cb[g.x], 1);
    atomicAdd(&cb[g.y], 1);
    atomicAdd(&cb[g.z], 1);
    atomicAdd(&cb[g.w], 1);
}

// ---- bucket: per b, sort groups by count into 10 buckets (0..8, 9=heavy).
// outputs: permT[slot]=t (bucket-ordered), gbase[t]=packed row base,
// bstart[b][11] group-bucket bounds, mbase[b][11] member-array bounds. ----
__global__ void __launch_bounds__(1024) hemp_bucket_kernel(const int* __restrict__ cnt,
                                                           ushort* __restrict__ permT,
                                                           int* __restrict__ gbase,
                                                           int* __restrict__ bstart,
                                                           int* __restrict__ mbase) {
    const int b = blockIdx.x;
    const int tid = threadIdx.x;
    __shared__ int whist[16][10];
    __shared__ int bs_s[11], mb_s[11], cur[10];
    const int wv = tid >> 6;
    if (tid < 160) whist[tid / 10][tid % 10] = 0;
    __syncthreads();
    const int* cb = cnt + (size_t)b * T;
    for (int t = tid; t < T; t += 1024) {
        int bc = min(cb[t], 9);
        atomicAdd(&whist[wv][bc], 1);
    }
    __syncthreads();
    if (tid < 10) {
        int h = 0;
        #pragma unroll
        for (int w = 0; w < 16; ++w) h += whist[w][tid];
        whist[0][tid] = h;
    }
    __syncthreads();
    if (tid == 0) {
        bs_s[0] = 0;
        mb_s[0] = 0;
        for (int i = 0; i < 10; ++i) {
            bs_s[i + 1] = bs_s[i] + whist[0][i];
            mb_s[i + 1] = mb_s[i] + whist[0][i] * ((i == 9) ? 8 : i);
        }
        for (int i = 0; i < 10; ++i) cur[i] = bs_s[i];
    }
    __syncthreads();
    for (int t = tid; t < T; t += 1024) {
        const int bc = min(cb[t], 9);
        const int slot = atomicAdd(&cur[bc], 1);
        permT[(size_t)b * T + slot] = (ushort)t;
        const int w = (bc == 9) ? 8 : bc;
        gbase[(size_t)b * T + t] = mb_s[bc] + (slot - bs_s[bc]) * w;
    }
    if (tid < 11) {
        bstart[b * 11 + tid] = bs_s[tid];
        mbase[b * 11 + tid] = mb_s[tid];
    }
}

// ---- fillPacked (int4): member n -> packed[gbase[g]+r]; r>=8 -> overflow ----
__global__ void __launch_bounds__(256) hemp_fill_kernel(const int* __restrict__ gid,
                                                        const int* __restrict__ gbase,
                                                        int* __restrict__ head2,
                                                        ushort* __restrict__ packed,
                                                        unsigned* __restrict__ of,
                                                        int* __restrict__ ocnt) {
    int idx = blockIdx.x * 256 + threadIdx.x;
    if (idx >= B * N / 4) return;
    const int b = idx / (N / 4);
    const int i4 = idx - b * (N / 4);
    const int4 g = reinterpret_cast<const int4*>(gid + (size_t)b * N)[i4];
    int* hb = head2 + b * T;
    const int* gbb = gbase + (size_t)b * T;
    ushort* pkb = packed + (size_t)b * N;
    const int n = i4 * 4;
    #pragma unroll
    for (int k = 0; k < 4; ++k) {
        const int gg = (k == 0) ? g.x : (k == 1) ? g.y : (k == 2) ? g.z : g.w;
        const int r = atomicAdd(&hb[gg], 1);
        if (r < 8) {
            pkb[gbb[gg] + r] = (ushort)(n + k);
        } else {
            int o = atomicAdd(&ocnt[b], 1);
            if (o < OCAP) of[b * OCAP + o] = ((unsigned)gg << 16) | (unsigned)(n + k);
        }
    }
}

// ---- fused: one block per (b,c). Row->LDS bf16; bucketed uniform-c reduce ----
__global__ void __launch_bounds__(FTH) hemp_fused_kernel(const float* __restrict__ feat,
                                                         const ushort* __restrict__ packed,
                                                         const ushort* __restrict__ permT,
                                                         const int* __restrict__ bstart,
                                                         const int* __restrict__ mbase,
                                                         const int* __restrict__ cnt,
                                                         const unsigned* __restrict__ of,
                                                         const int* __restrict__ ocnt,
                                                         float* __restrict__ out) {
    __shared__ ushort row_bf[N];  // 80000 B -> 2 blocks/CU
    const int tid = threadIdx.x;
    const int b = blockIdx.x >> 8;  // same-b blocks adjacent -> tables L2-hot
    const int c = blockIdx.x & 255;

    // Phase 1: stream feature row into LDS as bf16 (unroll-2 for load depth)
    const f32x4* __restrict__ f4 =
        reinterpret_cast<const f32x4*>(feat + (size_t)(b * C + c) * N);
    for (int i = tid; i < N / 4; i += 2 * FTH) {
        f32x4 v0 = f4[i];
        const int i2 = i + FTH;
        const bool ok = i2 < N / 4;
        f32x4 v1 = {};
        if (ok) v1 = f4[i2];
        u16x4 w0 = {f2bf(v0.x), f2bf(v0.y), f2bf(v0.z), f2bf(v0.w)};
        *reinterpret_cast<u16x4*>(&row_bf[i * 4]) = w0;
        if (ok) {
            u16x4 w1 = {f2bf(v1.x), f2bf(v1.y), f2bf(v1.z), f2bf(v1.w)};
            *reinterpret_cast<u16x4*>(&row_bf[i2 * 4]) = w1;
        }
    }
    __syncthreads();

    // Phase 2: buckets with wave-uniform member count.
    const int* bs = bstart + b * 11;
    const int* mb = mbase + b * 11;
    const ushort* __restrict__ pkb = packed + (size_t)b * N;
    const ushort* __restrict__ ptb = permT + (size_t)b * T;
    float* __restrict__ orow = out + (size_t)(b * C + c) * T;

    // bucket 0: empty groups -> 0
    for (int i = bs[0] + tid; i < bs[1]; i += FTH) orow[ptb[i]] = 0.0f;

    // buckets 1..8: exactly cb gathers per group, uniform 1/cb scale
    for (int cb = 1; cb <= 8; ++cb) {
        const int s0 = bs[cb], s1 = bs[cb + 1];
        const int base0 = mb[cb];
        const float invc = __builtin_amdgcn_rcpf((float)cb);
        for (int i = s0 + tid; i < s1; i += FTH) {
            const int base = base0 + (i - s0) * cb;
            float s = 0.0f;
            for (int k = 0; k < cb; ++k) s += bf2f(row_bf[pkb[base + k]]);
            orow[ptb[i]] = s * invc;
        }
    }

    // bucket 9 (heavy, cnt>=9, ~1/mesh): 8 packed + overflow scan
    {
        const int s0 = bs[9], s1 = bs[10];
        const int base0 = mb[9];
        const int O = min(ocnt[b], OCAP);
        const unsigned* __restrict__ ofb = of + b * OCAP;
        const int* __restrict__ cntb = cnt + b * T;
        for (int i = s0 + tid; i < s1; i += FTH) {
            const int g = ptb[i];
            const int base = base0 + (i - s0) * 8;
            float s = 0.0f;
            #pragma unroll
            for (int k = 0; k < 8; ++k) s += bf2f(row_bf[pkb[base + k]]);
            for (int e = 0; e < O; ++e) {
                unsigned w = ofb[e];
                if ((int)(w >> 16) == g) s += bf2f(row_bf[w & 0xFFFFu]);
            }
            orow[g] = s / (float)cntb[g];
        }
    }
}

// ---- fallback (ws too small): R2 LDS-atomic kernel ----
static constexpr int BLK = 1024;
__global__ void __launch_bounds__(256) hemp_zero_kernel(int* __restrict__ counts) {
    int i = blockIdx.x * 256 + threadIdx.x;
    if (i < B * T) counts[i] = 0;
}
__global__ void __launch_bounds__(256) hemp_count1_kernel(const int* __restrict__ gid,
                                                          int* __restrict__ counts) {
    int idx = blockIdx.x * 256 + threadIdx.x;
    if (idx < B * N) {
        int b = idx / N;
        atomicAdd(&counts[b * T + gid[idx]], 1);
    }
}
__global__ void __launch_bounds__(BLK) hemp_atomic_kernel(const float* __restrict__ feat,
                                                          const int* __restrict__ gid,
                                                          const int* __restrict__ counts,
                                                          float* __restrict__ out) {
    extern __shared__ float lds_sum[];
    const int tid = threadIdx.x;
    const int b = blockIdx.x >> 8;
    const int c = blockIdx.x & 255;
    float4* ls4 = reinterpret_cast<float4*>(lds_sum);
    for (int t = tid; t < T / 4; t += BLK) ls4[t] = make_float4(0.f, 0.f, 0.f, 0.f);
    __syncthreads();
    const float4* f4 = reinterpret_cast<const float4*>(feat + (size_t)(b * C + c) * N);
    const int4* g4 = reinterpret_cast<const int4*>(gid + (size_t)b * N);
    for (int i = tid; i < N / 4; i += BLK) {
        float4 v = f4[i];
        int4 g = g4[i];
        unsafeAtomicAdd(&lds_sum[g.x], v.x);
        unsafeAtomicAdd(&lds_sum[g.y], v.y);
        unsafeAtomicAdd(&lds_sum[g.z], v.z);
        unsafeAtomicAdd(&lds_sum[g.w], v.w);
    }
    __syncthreads();
    const int4* cnt4 = reinterpret_cast<const int4*>(counts + (size_t)b * T);
    float4* out4 = reinterpret_cast<float4*>(out + (size_t)(b * C + c) * T);
    for (int t = tid; t < T / 4; t += BLK) {
        int4 cn = cnt4[t];
        float4 s = ls4[t];
        float4 r;
        r.x = s.x / fmaxf((float)cn.x, 1.0f);
        r.y = s.y / fmaxf((float)cn.y, 1.0f);
        r.z = s.z / fmaxf((float)cn.z, 1.0f);
        r.w = s.w / fmaxf((float)cn.w, 1.0f);
        out4[t] = r;
    }
}

extern "C" void kernel_launch(void* const* d_in, const int* in_sizes, int n_in,
                              void* d_out, int out_size, void* d_ws, size_t ws_size,
                              hipStream_t stream) {
    const float* feat = (const float*)d_in[0];
    const int* gid = (const int*)d_in[1];
    float* out = (float*)d_out;

    // ws: cnt|head2|gbase [B*T] i32, packed[B*N] u16, permT[B*T] u16,
    //     bstart|mbase [B*11] i32, of[B*OCAP] u32, ocnt[B]   (~3 MB)
    char* p = (char*)d_ws;
    int* cnt = (int*)p;          p += (size_t)B * T * 4;
    int* head2 = (int*)p;        p += (size_t)B * T * 4;
    int* gbase = (int*)p;        p += (size_t)B * T * 4;
    ushort* packed = (ushort*)p; p += (size_t)B * N * 2;
    ushort* permT = (ushort*)p;  p += (size_t)B * T * 2;
    int* bstart = (int*)p;       p += (size_t)B * 11 * 4;
    int* mbase = (int*)p;        p += (size_t)B * 11 * 4 + 4;  // keep 16B-ish
    unsigned* of = (unsigned*)p; p += (size_t)B * OCAP * 4;
    int* ocnt = (int*)p;         p += (size_t)B * 4;
    size_t need = (size_t)(p - (char*)d_ws);

    if (ws_size >= need) {
        hemp_init_kernel<<<640, 256, 0, stream>>>(cnt, head2, ocnt);
        hemp_count_kernel<<<(B * N / 4 + 255) / 256, 256, 0, stream>>>(gid, cnt);
        hemp_bucket_kernel<<<B, 1024, 0, stream>>>(cnt, permT, gbase, bstart, mbase);
        hemp_fill_kernel<<<(B * N / 4 + 255) / 256, 256, 0, stream>>>(gid, gbase, head2,
                                                                      packed, of, ocnt);
        hemp_fused_kernel<<<B * C, FTH, 0, stream>>>(feat, packed, permT, bstart, mbase,
                                                     cnt, of, ocnt, out);
    } else {
        int* cnts = (int*)d_ws;
        hemp_zero_kernel<<<(B * T + 255) / 256, 256, 0, stream>>>(cnts);
        hemp_count1_kernel<<<(B * N + 255) / 256, 256, 0, stream>>>(gid, cnts);
        const size_t lds_bytes = (size_t)T * sizeof(float);
        hipFuncSetAttribute(reinterpret_cast<const void*>(hemp_atomic_kernel),
                            hipFuncAttributeMaxDynamicSharedMemorySize, (int)lds_bytes);
        hemp_atomic_kernel<<<B * C, BLK, lds_bytes, stream>>>(feat, gid, cnts, out);
    }
}

// Round 17
// 162.563 us; speedup vs baseline: 1.6605x; 1.6605x over previous
//
#include <hip/hip_runtime.h>

// HalfEdgeMeshPool: segment-mean over groups.
// feat: [B, C, N] f32, gid: [B, N] i32 in [0,T), out: [B, C, T] f32.
//
// R1/R2: LDS f32 atomics ~3.2cyc/lane -> 428us floor. R3: random 4B global
// gather = 14.5x over-fetch. R8/R11/R12: fused row-in-LDS + mt[t][8]+sentinel,
// 2x1024thr blocks -> 140us. R13-R16: every phase-2 micro-opt null or worse;
// bank conflicts (~7.7M) come from the N real gathers (sentinel pads are free
// broadcasts); scattered 4B stores amplify WRITE 4x (R10, R16).
// R17: attack the last consumer - phase serialization. One block per
// (b, 8-channel strip), 2x80KB LDS row buffers (160KB, 1 block/CU): stage
// channel j+1's row into REGISTERS while phase-2'ing channel j from LDS, then
// convert+ds_write after the barrier (T14 async-stage). Streaming overlaps
// gather/store; phase 2 and stores identical to proven R12.
static constexpr int B = 8;
static constexpr int C = 256;
static constexpr int N = 40000;
static constexpr int T = 20000;
static constexpr int PAD = 8;                  // mt slots per group
static constexpr int MAXH = N / (PAD + 1) + 8; // heavy-group cap per b
static constexpr int BUFU = 40448;             // u16 slots per buffer (incl zero pad)
static constexpr int KC = 8;                   // channels per block
static constexpr int FTH = 1024;               // fused block threads
static constexpr int NQ = 10;                  // staging regs: NQ * f32x4 per thread

typedef float  f32x4 __attribute__((ext_vector_type(4)));
typedef ushort u16x4 __attribute__((ext_vector_type(4)));
typedef ushort u16x8 __attribute__((ext_vector_type(8)));

__device__ __forceinline__ ushort f2bf(float v) {
    unsigned u = __float_as_uint(v);
    u += 0x7FFFu + ((u >> 16) & 1u);  // round-to-nearest-even
    return (ushort)(u >> 16);
}
__device__ __forceinline__ float bf2f(ushort u) {
    return __uint_as_float((unsigned)u << 16);
}

// ---- init: head=0, mt=sentinel(40000=0x9C40), hcnt=ocnt=0 ----
__global__ void __launch_bounds__(256) hemp_init_kernel(int* __restrict__ head,
                                                        unsigned* __restrict__ mt32,
                                                        int* __restrict__ hcnt,
                                                        int* __restrict__ ocnt) {
    const int stride = gridDim.x * 256;
    int i = blockIdx.x * 256 + threadIdx.x;
    for (int k = i; k < B * T * PAD / 2; k += stride) mt32[k] = 0x9C409C40u;
    for (int k = i; k < B * T; k += stride) head[k] = 0;
    if (i < B) { hcnt[i] = 0; ocnt[i] = 0; }
}

// ---- fill (int4): rank within group -> mt slot; overflow -> list ----
__global__ void __launch_bounds__(256) hemp_fill_kernel(const int* __restrict__ gid,
                                                        int* __restrict__ head,
                                                        ushort* __restrict__ mt,
                                                        unsigned* __restrict__ of,
                                                        int* __restrict__ hg,
                                                        int* __restrict__ hcnt,
                                                        int* __restrict__ ocnt) {
    int idx = blockIdx.x * 256 + threadIdx.x;
    if (idx >= B * N / 4) return;
    const int b = idx / (N / 4);
    const int i4 = idx - b * (N / 4);
    const int4 g = reinterpret_cast<const int4*>(gid + (size_t)b * N)[i4];
    int* hb = head + b * T;
    const int n = i4 * 4;
    #pragma unroll
    for (int k = 0; k < 4; ++k) {
        const int gg = (k == 0) ? g.x : (k == 1) ? g.y : (k == 2) ? g.z : g.w;
        const int r = atomicAdd(&hb[gg], 1);  // head ends as per-group count
        if (r < PAD) {
            mt[((size_t)(b * T + gg)) * PAD + r] = (ushort)(n + k);
        } else {
            int o = atomicAdd(&ocnt[b], 1);
            of[(size_t)b * N + o] = ((unsigned)gg << 16) | (unsigned)(n + k);
            if (r == PAD) {  // first overflow: register gg as heavy
                int h = atomicAdd(&hcnt[b], 1);
                hg[b * MAXH + h] = gg;
            }
        }
    }
}

// ---- phase 2 (R12-proven): 16B mt load, 8 gathers (sentinel=broadcast),
//      cnt load, rcp, coalesced NT store; heavy epilogue ----
__device__ __forceinline__ void phase2(const ushort* __restrict__ row_bf,
                                       const ushort* __restrict__ mtb,
                                       const int* __restrict__ cntb,
                                       const unsigned* __restrict__ ofb, int O,
                                       const int* __restrict__ hgb, int H,
                                       float* __restrict__ orow, int tid) {
    for (int t = tid; t < T; t += 2 * FTH) {
        const int t1 = t + FTH;
        const bool ok = t1 < T;
        u16x8 m0 = *reinterpret_cast<const u16x8*>(mtb + (size_t)t * PAD);
        u16x8 m1 = {};
        if (ok) m1 = *reinterpret_cast<const u16x8*>(mtb + (size_t)t1 * PAD);
        const int cn0 = cntb[t];
        const int cn1 = ok ? cntb[t1] : 0;
        float s0 = 0.0f, s1 = 0.0f;
        #pragma unroll
        for (int k = 0; k < PAD; ++k) {
            s0 += bf2f(row_bf[m0[k]]);
            s1 += bf2f(row_bf[m1[k]]);
        }
        if (cn0 <= PAD)
            __builtin_nontemporal_store(
                s0 * __builtin_amdgcn_rcpf(fmaxf((float)cn0, 1.0f)), orow + t);
        if (ok && cn1 <= PAD)
            __builtin_nontemporal_store(
                s1 * __builtin_amdgcn_rcpf(fmaxf((float)cn1, 1.0f)), orow + t1);
    }
    if (H > 0) {
        for (int i = tid; i < H; i += FTH) {
            const int g = hgb[i];
            const ushort* mg = mtb + (size_t)g * PAD;
            float s = 0.0f;
            #pragma unroll
            for (int k = 0; k < PAD; ++k) s += bf2f(row_bf[mg[k]]);
            for (int e = 0; e < O; ++e) {
                unsigned w = ofb[e];
                if ((int)(w >> 16) == g) s += bf2f(row_bf[w & 0xFFFFu]);
            }
            orow[g] = s / (float)cntb[g];
        }
    }
}

// ---- fused pipelined: block = (b, 8-channel strip); dbuf rows; async stage ----
__global__ void __launch_bounds__(FTH, 4) hemp_fused_kernel(const float* __restrict__ feat,
                                                            const ushort* __restrict__ mt,
                                                            const int* __restrict__ head,
                                                            const unsigned* __restrict__ of,
                                                            const int* __restrict__ hg,
                                                            const int* __restrict__ hcnt,
                                                            const int* __restrict__ ocnt,
                                                            float* __restrict__ out) {
    extern __shared__ ushort sh[];  // 2 * BUFU u16 = 161792 B -> 1 block/CU
    const int tid = threadIdx.x;
    const int blk = blockIdx.x;          // 256 blocks = 1 per CU
    const int b = blk >> 5;              // 32 blocks per b (adjacent -> mt L2-hot)
    const int cbase = (blk & 31) * KC;

    // zero sentinel pads of both buffers
    if (tid < (BUFU - N) / 4) {
        const u16x4 z = {0, 0, 0, 0};
        *reinterpret_cast<u16x4*>(&sh[N + tid * 4]) = z;
        *reinterpret_cast<u16x4*>(&sh[BUFU + N + tid * 4]) = z;
    }

    const ushort* __restrict__ mtb = mt + (size_t)b * T * PAD;
    const int* __restrict__ cntb = head + b * T;
    const int H = hcnt[b];
    const int O = ocnt[b];
    const unsigned* __restrict__ ofb = of + (size_t)b * N;
    const int* __restrict__ hgb = hg + b * MAXH;

    f32x4 r[NQ];
    // prologue: stage channel 0 into buf0
    {
        const f32x4* f4 = reinterpret_cast<const f32x4*>(feat + (size_t)(b * C + cbase) * N);
        #pragma unroll
        for (int q = 0; q < NQ; ++q) {
            const int i = tid + q * FTH;
            if (i < N / 4) r[q] = f4[i];
        }
        #pragma unroll
        for (int q = 0; q < NQ; ++q) {
            const int i = tid + q * FTH;
            if (i < N / 4) {
                u16x4 w = {f2bf(r[q].x), f2bf(r[q].y), f2bf(r[q].z), f2bf(r[q].w)};
                *reinterpret_cast<u16x4*>(&sh[i * 4]) = w;
            }
        }
    }
    __syncthreads();

    for (int j = 0; j < KC; ++j) {
        ushort* cur = sh + (size_t)(j & 1) * BUFU;
        ushort* nxt = sh + (size_t)((j & 1) ^ 1) * BUFU;
        // issue next channel's loads (results consumed after the barrier)
        if (j + 1 < KC) {
            const f32x4* f4 =
                reinterpret_cast<const f32x4*>(feat + (size_t)(b * C + cbase + j + 1) * N);
            #pragma unroll
            for (int q = 0; q < NQ; ++q) {
                const int i = tid + q * FTH;
                if (i < N / 4) r[q] = f4[i];
            }
        }
        // phase 2 on current buffer (overlaps the in-flight loads)
        phase2(cur, mtb, cntb, ofb, O, hgb, H,
               out + (size_t)(b * C + cbase + j) * T, tid);
        __syncthreads();
        // write staged registers into the other buffer
        if (j + 1 < KC) {
            #pragma unroll
            for (int q = 0; q < NQ; ++q) {
                const int i = tid + q * FTH;
                if (i < N / 4) {
                    u16x4 w = {f2bf(r[q].x), f2bf(r[q].y), f2bf(r[q].z), f2bf(r[q].w)};
                    *reinterpret_cast<u16x4*>(&nxt[i * 4]) = w;
                }
            }
        }
        __syncthreads();
    }
}

// ---- fallback (ws too small): R2 LDS-atomic kernel ----
static constexpr int BLK = 1024;
__global__ void __launch_bounds__(256) hemp_zero_kernel(int* __restrict__ counts) {
    int i = blockIdx.x * 256 + threadIdx.x;
    if (i < B * T) counts[i] = 0;
}
__global__ void __launch_bounds__(256) hemp_count1_kernel(const int* __restrict__ gid,
                                                          int* __restrict__ counts) {
    int idx = blockIdx.x * 256 + threadIdx.x;
    if (idx < B * N) {
        int b = idx / N;
        atomicAdd(&counts[b * T + gid[idx]], 1);
    }
}
__global__ void __launch_bounds__(BLK) hemp_atomic_kernel(const float* __restrict__ feat,
                                                          const int* __restrict__ gid,
                                                          const int* __restrict__ counts,
                                                          float* __restrict__ out) {
    extern __shared__ float lds_sum[];
    const int tid = threadIdx.x;
    const int b = blockIdx.x >> 8;
    const int c = blockIdx.x & 255;
    float4* ls4 = reinterpret_cast<float4*>(lds_sum);
    for (int t = tid; t < T / 4; t += BLK) ls4[t] = make_float4(0.f, 0.f, 0.f, 0.f);
    __syncthreads();
    const float4* f4 = reinterpret_cast<const float4*>(feat + (size_t)(b * C + c) * N);
    const int4* g4 = reinterpret_cast<const int4*>(gid + (size_t)b * N);
    for (int i = tid; i < N / 4; i += BLK) {
        float4 v = f4[i];
        int4 g = g4[i];
        unsafeAtomicAdd(&lds_sum[g.x], v.x);
        unsafeAtomicAdd(&lds_sum[g.y], v.y);
        unsafeAtomicAdd(&lds_sum[g.z], v.z);
        unsafeAtomicAdd(&lds_sum[g.w], v.w);
    }
    __syncthreads();
    const int4* cnt4 = reinterpret_cast<const int4*>(counts + (size_t)b * T);
    float4* out4 = reinterpret_cast<float4*>(out + (size_t)(b * C + c) * T);
    for (int t = tid; t < T / 4; t += BLK) {
        int4 cn = cnt4[t];
        float4 s = ls4[t];
        float4 r;
        r.x = s.x / fmaxf((float)cn.x, 1.0f);
        r.y = s.y / fmaxf((float)cn.y, 1.0f);
        r.z = s.z / fmaxf((float)cn.z, 1.0f);
        r.w = s.w / fmaxf((float)cn.w, 1.0f);
        out4[t] = r;
    }
}

extern "C" void kernel_launch(void* const* d_in, const int* in_sizes, int n_in,
                              void* d_out, int out_size, void* d_ws, size_t ws_size,
                              hipStream_t stream) {
    const float* feat = (const float*)d_in[0];
    const int* gid = (const int*)d_in[1];
    float* out = (float*)d_out;

    // ws: head[B*T] i32 | mt[B*T*PAD] u16 | of[B*N] u32 | hg[B*MAXH] i32 | hcnt[B] | ocnt[B]
    char* p = (char*)d_ws;
    int* head = (int*)p;            p += (size_t)B * T * 4;
    ushort* mt = (ushort*)p;        p += (size_t)B * T * PAD * 2;
    unsigned* of = (unsigned*)p;    p += (size_t)B * N * 4;
    int* hg = (int*)p;              p += (size_t)B * MAXH * 4;
    int* hcnt = (int*)p;            p += (size_t)B * 4;
    int* ocnt = (int*)p;            p += (size_t)B * 4;
    size_t need = (size_t)(p - (char*)d_ws);

    if (ws_size >= need) {
        hemp_init_kernel<<<2560, 256, 0, stream>>>(head, (unsigned*)mt, hcnt, ocnt);
        hemp_fill_kernel<<<(B * N / 4 + 255) / 256, 256, 0, stream>>>(gid, head, mt, of,
                                                                      hg, hcnt, ocnt);
        const int lds_bytes = 2 * BUFU * 2;  // 161792 B -> 1 block/CU
        hipFuncSetAttribute(reinterpret_cast<const void*>(hemp_fused_kernel),
                            hipFuncAttributeMaxDynamicSharedMemorySize, lds_bytes);
        hemp_fused_kernel<<<B * C / KC, FTH, lds_bytes, stream>>>(feat, mt, head, of, hg,
                                                                  hcnt, ocnt, out);
    } else {
        int* cnts = (int*)d_ws;
        hemp_zero_kernel<<<(B * T + 255) / 256, 256, 0, stream>>>(cnts);
        hemp_count1_kernel<<<(B * N + 255) / 256, 256, 0, stream>>>(gid, cnts);
        const size_t lds_bytes = (size_t)T * sizeof(float);
        hipFuncSetAttribute(reinterpret_cast<const void*>(hemp_atomic_kernel),
                            hipFuncAttributeMaxDynamicSharedMemorySize, (int)lds_bytes);
        hemp_atomic_kernel<<<B * C, BLK, lds_bytes, stream>>>(feat, gid, cnts, out);
    }
}

// Round 18
// 140.291 us; speedup vs baseline: 1.9241x; 1.1588x over previous
//
#include <hip/hip_runtime.h>

// HalfEdgeMeshPool: segment-mean over groups.
// feat: [B, C, N] f32, gid: [B, N] i32 in [0,T), out: [B, C, T] f32.
//
// FINAL (R18 = R12, the measured optimum at 140.4us):
// R1/R2: LDS f32 atomics serialize ~3.2 cyc/lane -> 428us floor.
// R3: random 4B global gather = 14.5x line over-fetch -> 1.7ms.
// R5/R6: sort+transpose (820MB, 2 passes) -> 250us.
// R7: fused single-pass, 160KB LDS -> 318us (1 block/CU, serialized phases).
// R8: fused, 80KB LDS, mt[t][8]+sentinel -> 199us. R11: 1024-thr blocks -> 142us.
// R12: int4 fill + rcp -> 140us.  <== this kernel
// R13-R17 all null/regressed: slot-major (VMEM), predication (compiler
// speculates LDS reads), cnt-popcount (L2 not the wall), cnt-bucketing
// (scattered 4B stores amplify WRITE 4x), explicit dbuf pipeline (halves
// occupancy; 2 independent blocks/CU already overlap phases).
static constexpr int B = 8;
static constexpr int C = 256;
static constexpr int N = 40000;
static constexpr int T = 20000;
static constexpr int PAD = 8;                  // mt slots per group (P(cnt>8)~1e-3)
static constexpr int MAXH = N / (PAD + 1) + 8; // heavy-group cap per b
static constexpr int LDSU = 40448;             // row_bf u16 slots (data + zero pad)
static constexpr int FTH = 1024;               // fused block threads

typedef float  f32x4 __attribute__((ext_vector_type(4)));
typedef ushort u16x4 __attribute__((ext_vector_type(4)));
typedef ushort u16x8 __attribute__((ext_vector_type(8)));

__device__ __forceinline__ ushort f2bf(float v) {
    unsigned u = __float_as_uint(v);
    u += 0x7FFFu + ((u >> 16) & 1u);  // round-to-nearest-even
    return (ushort)(u >> 16);
}
__device__ __forceinline__ float bf2f(ushort u) {
    return __uint_as_float((unsigned)u << 16);
}

// ---- init: head=0, mt=sentinel(40000=0x9C40), hcnt=ocnt=0 ----
__global__ void __launch_bounds__(256) hemp_init_kernel(int* __restrict__ head,
                                                        unsigned* __restrict__ mt32,
                                                        int* __restrict__ hcnt,
                                                        int* __restrict__ ocnt) {
    const int stride = gridDim.x * 256;
    int i = blockIdx.x * 256 + threadIdx.x;
    for (int k = i; k < B * T * PAD / 2; k += stride) mt32[k] = 0x9C409C40u;
    for (int k = i; k < B * T; k += stride) head[k] = 0;
    if (i < B) { hcnt[i] = 0; ocnt[i] = 0; }
}

// ---- fill (int4): rank within group -> mt slot; overflow -> list ----
__global__ void __launch_bounds__(256) hemp_fill_kernel(const int* __restrict__ gid,
                                                        int* __restrict__ head,
                                                        ushort* __restrict__ mt,
                                                        unsigned* __restrict__ of,
                                                        int* __restrict__ hg,
                                                        int* __restrict__ hcnt,
                                                        int* __restrict__ ocnt) {
    int idx = blockIdx.x * 256 + threadIdx.x;
    if (idx >= B * N / 4) return;
    const int b = idx / (N / 4);
    const int i4 = idx - b * (N / 4);
    const int4 g = reinterpret_cast<const int4*>(gid + (size_t)b * N)[i4];
    int* hb = head + b * T;
    const int n = i4 * 4;
    #pragma unroll
    for (int k = 0; k < 4; ++k) {
        const int gg = (k == 0) ? g.x : (k == 1) ? g.y : (k == 2) ? g.z : g.w;
        const int r = atomicAdd(&hb[gg], 1);  // head ends as per-group count
        if (r < PAD) {
            mt[((size_t)(b * T + gg)) * PAD + r] = (ushort)(n + k);
        } else {
            int o = atomicAdd(&ocnt[b], 1);
            of[(size_t)b * N + o] = ((unsigned)gg << 16) | (unsigned)(n + k);
            if (r == PAD) {  // first overflow: register gg as heavy
                int h = atomicAdd(&hcnt[b], 1);
                hg[b * MAXH + h] = gg;
            }
        }
    }
}

// ---- fused: one block per (b,c). Stream row->LDS bf16; 8-gather per group ----
__global__ void __launch_bounds__(FTH) hemp_fused_kernel(const float* __restrict__ feat,
                                                         const ushort* __restrict__ mt,
                                                         const int* __restrict__ head,
                                                         const unsigned* __restrict__ of,
                                                         const int* __restrict__ hg,
                                                         const int* __restrict__ hcnt,
                                                         const int* __restrict__ ocnt,
                                                         float* __restrict__ out) {
    extern __shared__ ushort row_bf[];  // LDSU u16 = 80896 B -> 2 blocks/CU
    const int tid = threadIdx.x;
    const int b = blockIdx.x >> 8;  // same-b blocks adjacent -> mt/cnt L2-hot
    const int c = blockIdx.x & 255;

    // zero the pad region (sentinel 40000 lands here)
    if (tid < (LDSU - N) / 4)
        *reinterpret_cast<u16x4*>(&row_bf[N + tid * 4]) = (u16x4){0, 0, 0, 0};

    // Phase 1: stream feature row into LDS as bf16 (unroll-2 for load depth)
    const f32x4* __restrict__ f4 =
        reinterpret_cast<const f32x4*>(feat + (size_t)(b * C + c) * N);
    for (int i = tid; i < N / 4; i += 2 * FTH) {
        f32x4 v0 = f4[i];
        const int i2 = i + FTH;
        const bool ok = i2 < N / 4;
        f32x4 v1 = {};
        if (ok) v1 = f4[i2];
        u16x4 w0 = {f2bf(v0.x), f2bf(v0.y), f2bf(v0.z), f2bf(v0.w)};
        *reinterpret_cast<u16x4*>(&row_bf[i * 4]) = w0;
        if (ok) {
            u16x4 w1 = {f2bf(v1.x), f2bf(v1.y), f2bf(v1.z), f2bf(v1.w)};
            *reinterpret_cast<u16x4*>(&row_bf[i2 * 4]) = w1;
        }
    }
    __syncthreads();

    // Phase 2: unroll-2 (two independent chains): per group one 16B coalesced
    // mt load + 4B cnt + 8 LDS gathers (sentinel = free broadcast) + rcp +
    // coalesced NT store.
    const ushort* __restrict__ mtb = mt + (size_t)b * T * PAD;
    const int* __restrict__ cntb = head + b * T;
    float* __restrict__ orow = out + (size_t)(b * C + c) * T;
    for (int t = tid; t < T; t += 2 * FTH) {
        const int t1 = t + FTH;
        const bool ok = t1 < T;
        u16x8 m0 = *reinterpret_cast<const u16x8*>(mtb + (size_t)t * PAD);
        u16x8 m1 = {};
        if (ok) m1 = *reinterpret_cast<const u16x8*>(mtb + (size_t)t1 * PAD);
        int cn0 = cntb[t];
        int cn1 = ok ? cntb[t1] : 0;
        float s0 = ((bf2f(row_bf[m0[0]]) + bf2f(row_bf[m0[1]])) +
                    (bf2f(row_bf[m0[2]]) + bf2f(row_bf[m0[3]]))) +
                   ((bf2f(row_bf[m0[4]]) + bf2f(row_bf[m0[5]])) +
                    (bf2f(row_bf[m0[6]]) + bf2f(row_bf[m0[7]])));
        if (cn0 <= PAD)
            __builtin_nontemporal_store(
                s0 * __builtin_amdgcn_rcpf(fmaxf((float)cn0, 1.0f)), orow + t);
        if (ok) {
            float s1 = ((bf2f(row_bf[m1[0]]) + bf2f(row_bf[m1[1]])) +
                        (bf2f(row_bf[m1[2]]) + bf2f(row_bf[m1[3]]))) +
                       ((bf2f(row_bf[m1[4]]) + bf2f(row_bf[m1[5]])) +
                        (bf2f(row_bf[m1[6]]) + bf2f(row_bf[m1[7]])));
            if (cn1 <= PAD)
                __builtin_nontemporal_store(
                    s1 * __builtin_amdgcn_rcpf(fmaxf((float)cn1, 1.0f)), orow + t1);
        }
    }

    // Epilogue: heavy groups (count>PAD, ~22 per mesh) — mt + overflow scan
    const int H = hcnt[b];
    if (H > 0) {
        const int O = ocnt[b];
        const unsigned* __restrict__ ofb = of + (size_t)b * N;
        for (int i = tid; i < H; i += FTH) {
            const int g = hg[b * MAXH + i];
            const ushort* mg = mtb + (size_t)g * PAD;
            float s = 0.0f;
            #pragma unroll
            for (int k = 0; k < PAD; ++k) s += bf2f(row_bf[mg[k]]);
            for (int e = 0; e < O; ++e) {
                unsigned w = ofb[e];
                if ((w >> 16) == (unsigned)g) s += bf2f(row_bf[w & 0xFFFFu]);
            }
            orow[g] = s / (float)cntb[g];
        }
    }
}

// ---- fallback (ws too small): R2 LDS-atomic kernel ----
static constexpr int BLK = 1024;
__global__ void __launch_bounds__(256) hemp_zero_kernel(int* __restrict__ counts) {
    int i = blockIdx.x * 256 + threadIdx.x;
    if (i < B * T) counts[i] = 0;
}
__global__ void __launch_bounds__(256) hemp_count1_kernel(const int* __restrict__ gid,
                                                          int* __restrict__ counts) {
    int idx = blockIdx.x * 256 + threadIdx.x;
    if (idx < B * N) {
        int b = idx / N;
        atomicAdd(&counts[b * T + gid[idx]], 1);
    }
}
__global__ void __launch_bounds__(BLK) hemp_atomic_kernel(const float* __restrict__ feat,
                                                          const int* __restrict__ gid,
                                                          const int* __restrict__ counts,
                                                          float* __restrict__ out) {
    extern __shared__ float lds_sum[];
    const int tid = threadIdx.x;
    const int b = blockIdx.x >> 8;
    const int c = blockIdx.x & 255;
    float4* ls4 = reinterpret_cast<float4*>(lds_sum);
    for (int t = tid; t < T / 4; t += BLK) ls4[t] = make_float4(0.f, 0.f, 0.f, 0.f);
    __syncthreads();
    const float4* f4 = reinterpret_cast<const float4*>(feat + (size_t)(b * C + c) * N);
    const int4* g4 = reinterpret_cast<const int4*>(gid + (size_t)b * N);
    for (int i = tid; i < N / 4; i += BLK) {
        float4 v = f4[i];
        int4 g = g4[i];
        unsafeAtomicAdd(&lds_sum[g.x], v.x);
        unsafeAtomicAdd(&lds_sum[g.y], v.y);
        unsafeAtomicAdd(&lds_sum[g.z], v.z);
        unsafeAtomicAdd(&lds_sum[g.w], v.w);
    }
    __syncthreads();
    const int4* cnt4 = reinterpret_cast<const int4*>(counts + (size_t)b * T);
    float4* out4 = reinterpret_cast<float4*>(out + (size_t)(b * C + c) * T);
    for (int t = tid; t < T / 4; t += BLK) {
        int4 cn = cnt4[t];
        float4 s = ls4[t];
        float4 r;
        r.x = s.x / fmaxf((float)cn.x, 1.0f);
        r.y = s.y / fmaxf((float)cn.y, 1.0f);
        r.z = s.z / fmaxf((float)cn.z, 1.0f);
        r.w = s.w / fmaxf((float)cn.w, 1.0f);
        out4[t] = r;
    }
}

extern "C" void kernel_launch(void* const* d_in, const int* in_sizes, int n_in,
                              void* d_out, int out_size, void* d_ws, size_t ws_size,
                              hipStream_t stream) {
    const float* feat = (const float*)d_in[0];
    const int* gid = (const int*)d_in[1];
    float* out = (float*)d_out;

    // ws: head[B*T] i32 | mt[B*T*PAD] u16 | of[B*N] u32 | hg[B*MAXH] i32 | hcnt[B] | ocnt[B]
    char* p = (char*)d_ws;
    int* head = (int*)p;            p += (size_t)B * T * 4;
    ushort* mt = (ushort*)p;        p += (size_t)B * T * PAD * 2;
    unsigned* of = (unsigned*)p;    p += (size_t)B * N * 4;
    int* hg = (int*)p;              p += (size_t)B * MAXH * 4;
    int* hcnt = (int*)p;            p += (size_t)B * 4;
    int* ocnt = (int*)p;            p += (size_t)B * 4;
    size_t need = (size_t)(p - (char*)d_ws);

    if (ws_size >= need) {
        hemp_init_kernel<<<2560, 256, 0, stream>>>(head, (unsigned*)mt, hcnt, ocnt);
        hemp_fill_kernel<<<(B * N / 4 + 255) / 256, 256, 0, stream>>>(gid, head, mt, of,
                                                                      hg, hcnt, ocnt);
        const int lds_bytes = LDSU * 2;  // 80896 B -> 2 blocks/CU
        hipFuncSetAttribute(reinterpret_cast<const void*>(hemp_fused_kernel),
                            hipFuncAttributeMaxDynamicSharedMemorySize, lds_bytes);
        hemp_fused_kernel<<<B * C, FTH, lds_bytes, stream>>>(feat, mt, head, of, hg,
                                                             hcnt, ocnt, out);
    } else {
        int* cnts = (int*)d_ws;
        hemp_zero_kernel<<<(B * T + 255) / 256, 256, 0, stream>>>(cnts);
        hemp_count1_kernel<<<(B * N + 255) / 256, 256, 0, stream>>>(gid, cnts);
        const size_t lds_bytes = (size_t)T * sizeof(float);
        hipFuncSetAttribute(reinterpret_cast<const void*>(hemp_atomic_kernel),
                            hipFuncAttributeMaxDynamicSharedMemorySize, (int)lds_bytes);
        hemp_atomic_kernel<<<B * C, BLK, lds_bytes, stream>>>(feat, gid, cnts, out);
    }
}